// Round 10
// baseline (168.878 us; speedup 1.0000x reference)
//
#include <hip/hip_runtime.h>

#define SEQ 2048
#define BSZ 2
#define NH 16
#define DKD 64
#define DM 1024
#define NROW (SEQ*BSZ)   // 4096
#define KDIM 1024
#define BIAS 16.0f       // fixed exp2-domain shift (s' std ~1.4, max ~8)

typedef __attribute__((ext_vector_type(8))) short bf16x8;
typedef __attribute__((ext_vector_type(4))) short bf16x4;
typedef __attribute__((ext_vector_type(4))) float floatx4;
typedef __attribute__((ext_vector_type(2))) unsigned uint2v;

__device__ __forceinline__ unsigned short f2b(float f) {
  unsigned int u = __builtin_bit_cast(unsigned int, f);
  u += 0x7fffu + ((u >> 16) & 1u);
  return (unsigned short)(u >> 16);
}

__device__ __forceinline__ void async_copy16(void* lds, const void* g) {
  __builtin_amdgcn_global_load_lds(
      (__attribute__((address_space(1))) void*)(void*)g,
      (__attribute__((address_space(3))) void*)lds, 16, 0, 0);
}

__device__ __forceinline__ floatx4 mfma16(bf16x8 a, bf16x8 b, floatx4 c) {
  return __builtin_amdgcn_mfma_f32_16x16x32_bf16(a, b, c, 0, 0, 0);
}

// K=16 bf16 MFMA: consumes P straight from S^T C-layout registers.
__device__ __forceinline__ floatx4 mfma16k(bf16x4 a, bf16x4 b, floatx4 c) {
#if __has_builtin(__builtin_amdgcn_mfma_f32_16x16x16bf16_1k)
  return __builtin_amdgcn_mfma_f32_16x16x16bf16_1k(a, b, c, 0, 0, 0);
#else
  floatx4 d;
  asm volatile("v_mfma_f32_16x16x16_bf16 %0, %1, %2, %3"
               : "=v"(d) : "v"(a), "v"(b), "v"(c));
  return d;
#endif
}

// ---------------- fp32 -> bf16 conversion of x and W(q,k,v) ----------------
__global__ __launch_bounds__(256) void cvt_kernel(
    const float* __restrict__ x, const float* __restrict__ Wq,
    const float* __restrict__ Wk, const float* __restrict__ Wv,
    ushort* __restrict__ xbf, ushort* __restrict__ wbf) {
  size_t tid = (size_t)blockIdx.x * 256 + threadIdx.x;
  size_t i4 = tid * 4;
  const float* src;
  const size_t NX = (size_t)NROW * KDIM;  // 4194304
  ushort* dst;
  size_t off;
  if (i4 < NX) {
    src = x; off = i4; dst = xbf + i4;
  } else {
    size_t wix = i4 - NX;                 // 0 .. 3*1048576
    int proj = (int)(wix >> 20);
    src = proj == 0 ? Wq : (proj == 1 ? Wk : Wv);
    off = wix & 1048575u;
    dst = wbf + wix;
  }
  float4 v = *(const float4*)(src + off);
  ushort4 o;
  o.x = f2b(v.x); o.y = f2b(v.y); o.z = f2b(v.z); o.w = f2b(v.w);
  *(ushort4*)dst = o;
}

// ---------------- QKV projection GEMM: C[4096][3072] = Xbf * Wbf^T ----------
// Known-good: BK=32, Cl epilogue unioned over Al/Bl (35 KB LDS),
// launch_bounds(256,3): 768-block grid fully co-resident, no tail.
union GemmSmem {
  struct { ushort Al[128 * 32]; ushort Bl[128 * 32]; } ab;
  ushort Cl[128 * 136];
};

__global__ __launch_bounds__(256, 3) void gemm_qkv(
    const ushort* __restrict__ xbf, const ushort* __restrict__ wbf,
    const float* __restrict__ bq, const float* __restrict__ bk,
    const float* __restrict__ bvv,
    ushort* __restrict__ Qs, ushort* __restrict__ Ks, ushort* __restrict__ Vt) {
  __shared__ GemmSmem sm;
  const int t = threadIdx.x;
  const int w = t >> 6, l = t & 63;
  const int wr = w >> 1, wc = w & 1;
  const int lane15 = l & 15, quad = l >> 4;
  const int rb = blockIdx.x, cb = blockIdx.y;
  const ushort* Ag = xbf + (size_t)rb * 128 * KDIM;
  const ushort* Bg = wbf + (size_t)cb * 128 * KDIM;
  const int rsub = l >> 2, c2 = (l & 3) * 8;

  floatx4 acc[4][4];
  #pragma unroll
  for (int i = 0; i < 4; ++i)
    #pragma unroll
    for (int j = 0; j < 4; ++j) acc[i][j] = (floatx4){0.f, 0.f, 0.f, 0.f};

  for (int kk = 0; kk < KDIM; kk += 32) {
    __syncthreads();
    #pragma unroll
    for (int half = 0; half < 2; ++half) {
      int rloc = w * 32 + half * 16;
      async_copy16(&sm.ab.Al[rloc * 32], Ag + (size_t)(rloc + rsub) * KDIM + kk + c2);
      async_copy16(&sm.ab.Bl[rloc * 32], Bg + (size_t)(rloc + rsub) * KDIM + kk + c2);
    }
    __syncthreads();
    bf16x8 af[4], bfr[4];
    #pragma unroll
    for (int mt = 0; mt < 4; ++mt)
      af[mt] = *(const bf16x8*)&sm.ab.Al[(wr * 64 + mt * 16 + lane15) * 32 + quad * 8];
    #pragma unroll
    for (int nt = 0; nt < 4; ++nt)
      bfr[nt] = *(const bf16x8*)&sm.ab.Bl[(wc * 64 + nt * 16 + lane15) * 32 + quad * 8];
    #pragma unroll
    for (int mt = 0; mt < 4; ++mt)
      #pragma unroll
      for (int nt = 0; nt < 4; ++nt)
        acc[mt][nt] = mfma16(af[mt], bfr[nt], acc[mt][nt]);
  }
  __syncthreads();   // Al/Bl reads done before Cl (aliased) is written

  int proj = (cb * 128) >> 10;                 // uniform per block
  const float* bias = proj == 0 ? bq : (proj == 1 ? bk : bvv);
  float scale = proj == 0 ? 0.125f * 1.44269504088896f : 1.0f;
  bool isV = (proj == 2);

  #pragma unroll
  for (int nt = 0; nt < 4; ++nt) {
    int c = wc * 64 + nt * 16 + lane15;
    int cip = (cb * 128 + c) & 1023;
    float bias_v = bias[cip];
    #pragma unroll
    for (int mt = 0; mt < 4; ++mt) {
      #pragma unroll
      for (int r = 0; r < 4; ++r) {
        int n = wr * 64 + mt * 16 + quad * 4 + r;
        float val = (acc[mt][nt][r] + bias_v) * scale;
        if (!isV) sm.Cl[n * 136 + c] = f2b(val);
        else      sm.Cl[c * 136 + (n & 1) * 64 + (n >> 1)] = f2b(val);
      }
    }
  }
  __syncthreads();

  if (!isV) {
    ushort* dst = proj == 0 ? Qs : Ks;
    int b = t >> 7;
    int sl = t & 63;
    int chunk = (t >> 6) & 1;
    int n = (sl << 1) | b;
    int cip = (cb * 128 + chunk * 64) & 1023;
    int h = cip >> 6;
    int s = rb * 64 + sl;
    ushort* g = dst + (((size_t)(b * NH + h) * SEQ + s) * DKD);
    const uint4* s4 = (const uint4*)&sm.Cl[n * 136 + chunk * 64];
    #pragma unroll
    for (int j = 0; j < 8; ++j) *(uint4*)(g + j * 8) = s4[j];
  } else {
    int c = t >> 1, b = t & 1;
    int cip = (cb * 128 + c) & 1023;
    int h = cip >> 6, dk = c & 63;
    ushort* g = Vt + ((size_t)(b * NH + h) * DKD + dk) * SEQ + rb * 64;
    const uint4* s4 = (const uint4*)&sm.Cl[c * 136 + b * 64];
    #pragma unroll
    for (int j = 0; j < 8; ++j) *(uint4*)(g + j * 8) = s4[j];
  }
}

// ---------------- fused causal attention with softmax-one -------------------
// 128-thread blocks (2 waves x 16 q-rows = 32-row q-tiles), paired qa/63-qa:
// 1024 blocks x exactly 33 iterations -> 4 blocks/CU, 16 waves/CU (2x round
// 9's occupancy; grid was the binding limit). K/V tiles stay 64-wide,
// block-shared, staged via swizzled global_load_lds double buffer (32 KB).
// S^T-in-registers P, fixed-bias exp2 softmax, deferred max.
__global__ __launch_bounds__(128, 4) void attn_kernel(
    const ushort* __restrict__ Qs, const ushort* __restrict__ Ks,
    const ushort* __restrict__ Vt, float* __restrict__ out) {
  __shared__ ushort Kl[2][64 * 64];
  __shared__ ushort Vl[2][64 * 64];
  const int t = threadIdx.x;
  const int w = t >> 6, l = t & 63;    // w in {0,1}
  const int lane15 = l & 15, quad = l >> 4;
  const int bh = blockIdx.x;            // fast dim -> K/V locality per XCD
  const int qa = blockIdx.y;            // 0..31 (32-row q-tile index, phase A)
  const int b = bh >> 4, h = bh & 15;
  const int lastA = qa >> 1;            // last k-tile iteration of phase A

  const ushort* Kg = Ks + (size_t)bh * SEQ * DKD;
  const ushort* Vg = Vt + (size_t)bh * DKD * SEQ;
  const int g8 = l >> 3;                // row within 8-row staging group
  const int gch = ((l & 7) ^ g8) * 8;   // swizzled global chunk (shorts)
  const int sw = lane15 & 7;            // fragment-read swizzle

  int qt = qa;                          // 32-row q-tile index
  int qbase = qt * 32;
  const ushort* Qg = Qs + ((size_t)bh * SEQ + qbase + w * 16 + lane15) * DKD;
  bf16x8 qf0 = *(const bf16x8*)(Qg + quad * 8);
  bf16x8 qf1 = *(const bf16x8*)(Qg + 32 + quad * 8);

  floatx4 o[4];
  #pragma unroll
  for (int i = 0; i < 4; ++i) o[i] = (floatx4){0.f, 0.f, 0.f, 0.f};
  floatx4 lacc = (floatx4){0.f, 0.f, 0.f, 0.f};
  float pm = -1e30f;                    // per-lane deferred max (q = lane15)

  bf16x4 ones4;
  #pragma unroll
  for (int j = 0; j < 4; ++j) ones4[j] = (short)0x3F80;  // bf16 1.0

  #define KT_OF(j) ((j) <= lastA ? (j) : (j) - lastA - 1)

  // async stage 64x64 K and V tiles: 2 waves x 4 calls x 8 rows each.
  #define STAGE(BUF, KT) do {                                                \
    _Pragma("unroll")                                                        \
    for (int c = 0; c < 4; ++c) {                                            \
      int rr = c * 16 + w * 8;                                               \
      async_copy16(&Kl[BUF][rr * 64],                                        \
                   Kg + (size_t)((KT) * 64 + rr + g8) * DKD + gch);          \
      async_copy16(&Vl[BUF][rr * 64],                                        \
                   Vg + (size_t)(rr + g8) * SEQ + (KT) * 64 + gch);          \
    } } while (0)

  STAGE(0, 0);

  for (int it = 0; it <= 32; ++it) {
    const int cur = it & 1;
    const int kt = KT_OF(it);
    const bool edge = (it == lastA) || (it == 32);
    __syncthreads();                    // drains last iter's loads (vmcnt)
    if (it < 32) STAGE(cur ^ 1, KT_OF(it + 1));

    // S^T tile: A = K-frag (m = k_s), B = Q-frag (n = q)
    floatx4 sf[4];
    #pragma unroll
    for (int nt = 0; nt < 4; ++nt) {
      floatx4 a = (floatx4){-BIAS, -BIAS, -BIAS, -BIAS};
      int row = nt * 16 + lane15;
      bf16x8 k0 = *(const bf16x8*)&Kl[cur][row * 64 + ((quad ^ sw) * 8)];
      bf16x8 k1 = *(const bf16x8*)&Kl[cur][row * 64 + (((quad + 4) ^ sw) * 8)];
      a = mfma16(k0, qf0, a);
      a = mfma16(k1, qf1, a);
      sf[nt] = a;   // (k = kt*64+nt*16+quad*4+r, q = qbase+w*16+lane15)
    }

    if (edge) {  // final k-tile of this phase: causal mask (k > q)
      int q_abs = qbase + w * 16 + lane15;
      #pragma unroll
      for (int nt = 0; nt < 4; ++nt)
        #pragma unroll
        for (int r = 0; r < 4; ++r) {
          int k_abs = kt * 64 + nt * 16 + quad * 4 + r;
          if (k_abs > q_abs) sf[nt][r] = -1e30f;
        }
    }

    // exp2 + deferred per-lane max + pack to bf16x4 A-fragments
    bf16x4 pa[4];
    #pragma unroll
    for (int nt = 0; nt < 4; ++nt) {
      float p0 = __builtin_amdgcn_exp2f(sf[nt][0]);
      float p1 = __builtin_amdgcn_exp2f(sf[nt][1]);
      float p2 = __builtin_amdgcn_exp2f(sf[nt][2]);
      float p3 = __builtin_amdgcn_exp2f(sf[nt][3]);
      pm = fmaxf(pm, fmaxf(fmaxf(sf[nt][0], sf[nt][1]),
                           fmaxf(sf[nt][2], sf[nt][3])));
      unsigned u0 = __builtin_bit_cast(unsigned, p0);
      unsigned u1 = __builtin_bit_cast(unsigned, p1);
      unsigned u2 = __builtin_bit_cast(unsigned, p2);
      unsigned u3 = __builtin_bit_cast(unsigned, p3);
      uint2v pk;
      pk[0] = (u0 >> 16) | (u1 & 0xffff0000u);
      pk[1] = (u2 >> 16) | (u3 & 0xffff0000u);
      pa[nt] = __builtin_bit_cast(bf16x4, pk);
    }

    // row-sum via MFMA (ones B) and PV, P consumed directly from registers
    #pragma unroll
    for (int nt = 0; nt < 4; ++nt) lacc = mfma16k(pa[nt], ones4, lacc);
    #pragma unroll
    for (int ntd = 0; ntd < 4; ++ntd) {
      int row = ntd * 16 + lane15;
      #pragma unroll
      for (int nt = 0; nt < 4; ++nt) {
        int ch = nt * 2 + (quad >> 1);
        bf16x4 vf = *(const bf16x4*)&Vl[cur][row * 64 + ((ch ^ sw) * 8) +
                                            (quad & 1) * 4];
        o[ntd] = mfma16k(pa[nt], vf, o[ntd]);
      }
    }

    // flush finished q-tile
    if (edge) {
      float pmr = fmaxf(pm, __shfl_xor(pm, 16, 64));
      pmr = fmaxf(pmr, __shfl_xor(pmr, 32, 64));
      float inv_[4];
      #pragma unroll
      for (int r = 0; r < 4; ++r) {
        float mq = __shfl(pmr, quad * 4 + r, 64);  // max for q = quad*4+r
        inv_[r] = 1.0f / (__builtin_amdgcn_exp2f(mq) + lacc[r]);
      }
      #pragma unroll
      for (int ntd = 0; ntd < 4; ++ntd) {
        int d = h * DKD + ntd * 16 + lane15;
        #pragma unroll
        for (int r = 0; r < 4; ++r) {
          int i = qbase + w * 16 + quad * 4 + r;
          out[((size_t)i * BSZ + b) * DM + d] = o[ntd][r] * inv_[r];
        }
      }
      if (it == lastA) {  // switch to phase B (q-tile 63-qa)
        #pragma unroll
        for (int i = 0; i < 4; ++i) o[i] = (floatx4){0.f, 0.f, 0.f, 0.f};
        lacc = (floatx4){0.f, 0.f, 0.f, 0.f};
        pm = -1e30f;
        qt = 63 - qa;
        qbase = qt * 32;
        const ushort* Qg2 = Qs + ((size_t)bh * SEQ + qbase + w * 16 + lane15) * DKD;
        qf0 = *(const bf16x8*)(Qg2 + quad * 8);
        qf1 = *(const bf16x8*)(Qg2 + 32 + quad * 8);
      }
    }
  }
  #undef STAGE
  #undef KT_OF
}

extern "C" void kernel_launch(void* const* d_in, const int* in_sizes, int n_in,
                              void* d_out, int out_size, void* d_ws, size_t ws_size,
                              hipStream_t stream) {
  (void)in_sizes; (void)n_in; (void)out_size; (void)ws_size;
  const float* x  = (const float*)d_in[0];
  const float* Wq = (const float*)d_in[1];
  const float* bq = (const float*)d_in[2];
  const float* Wk = (const float*)d_in[3];
  const float* bk = (const float*)d_in[4];
  const float* Wv = (const float*)d_in[5];
  const float* bv = (const float*)d_in[6];
  float* out = (float*)d_out;

  // cvt staging lives inside d_out (16 MB): xbf 8 MB + wbf 6 MB.
  ushort* xbf = (ushort*)d_out;                       // [0, 8 MB)
  ushort* wbf = (ushort*)((char*)d_out + 8388608);    // [8 MB, 14.67 MB)

  // d_ws usage: 24 MB total.
  char* ws = (char*)d_ws;
  ushort* Qs = (ushort*)(ws);               // [0, 8 MB)
  ushort* Ks = (ushort*)(ws + 8388608);     // [8 MB, 16 MB)
  ushort* Vt = (ushort*)(ws + 16777216);    // [16 MB, 24 MB)

  cvt_kernel<<<dim3(7168), dim3(256), 0, stream>>>(x, Wq, Wk, Wv, xbf, wbf);
  gemm_qkv<<<dim3(32, 24), dim3(256), 0, stream>>>(xbf, wbf, bq, bk, bv, Qs, Ks, Vt);
  attn_kernel<<<dim3(32, 32), dim3(128), 0, stream>>>(Qs, Ks, Vt, out);
}

// Round 11
// 161.827 us; speedup vs baseline: 1.0436x; 1.0436x over previous
//
#include <hip/hip_runtime.h>

#define SEQ 2048
#define BSZ 2
#define NH 16
#define DKD 64
#define DM 1024
#define NROW (SEQ*BSZ)   // 4096
#define KDIM 1024
#define BIAS 16.0f       // fixed exp2-domain shift (s' std ~1.4, max ~8)

typedef __attribute__((ext_vector_type(8))) short bf16x8;
typedef __attribute__((ext_vector_type(4))) short bf16x4;
typedef __attribute__((ext_vector_type(4))) float floatx4;
typedef __attribute__((ext_vector_type(2))) unsigned uint2v;

__device__ __forceinline__ unsigned short f2b(float f) {
  unsigned int u = __builtin_bit_cast(unsigned int, f);
  u += 0x7fffu + ((u >> 16) & 1u);
  return (unsigned short)(u >> 16);
}

__device__ __forceinline__ void async_copy16(void* lds, const void* g) {
  __builtin_amdgcn_global_load_lds(
      (__attribute__((address_space(1))) void*)(void*)g,
      (__attribute__((address_space(3))) void*)lds, 16, 0, 0);
}

__device__ __forceinline__ floatx4 mfma16(bf16x8 a, bf16x8 b, floatx4 c) {
  return __builtin_amdgcn_mfma_f32_16x16x32_bf16(a, b, c, 0, 0, 0);
}

// K=16 bf16 MFMA: consumes P straight from S^T C-layout registers.
__device__ __forceinline__ floatx4 mfma16k(bf16x4 a, bf16x4 b, floatx4 c) {
#if __has_builtin(__builtin_amdgcn_mfma_f32_16x16x16bf16_1k)
  return __builtin_amdgcn_mfma_f32_16x16x16bf16_1k(a, b, c, 0, 0, 0);
#else
  floatx4 d;
  asm volatile("v_mfma_f32_16x16x16_bf16 %0, %1, %2, %3"
               : "=v"(d) : "v"(a), "v"(b), "v"(c));
  return d;
#endif
}

// ---------------- fp32 -> bf16 conversion of x and W(q,k,v) ----------------
__global__ __launch_bounds__(256) void cvt_kernel(
    const float* __restrict__ x, const float* __restrict__ Wq,
    const float* __restrict__ Wk, const float* __restrict__ Wv,
    ushort* __restrict__ xbf, ushort* __restrict__ wbf) {
  size_t tid = (size_t)blockIdx.x * 256 + threadIdx.x;
  size_t i4 = tid * 4;
  const float* src;
  const size_t NX = (size_t)NROW * KDIM;  // 4194304
  ushort* dst;
  size_t off;
  if (i4 < NX) {
    src = x; off = i4; dst = xbf + i4;
  } else {
    size_t wix = i4 - NX;                 // 0 .. 3*1048576
    int proj = (int)(wix >> 20);
    src = proj == 0 ? Wq : (proj == 1 ? Wk : Wv);
    off = wix & 1048575u;
    dst = wbf + wix;
  }
  float4 v = *(const float4*)(src + off);
  ushort4 o;
  o.x = f2b(v.x); o.y = f2b(v.y); o.z = f2b(v.z); o.w = f2b(v.w);
  *(ushort4*)dst = o;
}

// ---------------- QKV projection GEMM: C[4096][3072] = Xbf * Wbf^T ----------
// Known-good: BK=32, Cl epilogue unioned over Al/Bl (35 KB LDS),
// launch_bounds(256,3): 768-block grid fully co-resident, no tail.
union GemmSmem {
  struct { ushort Al[128 * 32]; ushort Bl[128 * 32]; } ab;
  ushort Cl[128 * 136];
};

__global__ __launch_bounds__(256, 3) void gemm_qkv(
    const ushort* __restrict__ xbf, const ushort* __restrict__ wbf,
    const float* __restrict__ bq, const float* __restrict__ bk,
    const float* __restrict__ bvv,
    ushort* __restrict__ Qs, ushort* __restrict__ Ks, ushort* __restrict__ Vt) {
  __shared__ GemmSmem sm;
  const int t = threadIdx.x;
  const int w = t >> 6, l = t & 63;
  const int wr = w >> 1, wc = w & 1;
  const int lane15 = l & 15, quad = l >> 4;
  const int rb = blockIdx.x, cb = blockIdx.y;
  const ushort* Ag = xbf + (size_t)rb * 128 * KDIM;
  const ushort* Bg = wbf + (size_t)cb * 128 * KDIM;
  const int rsub = l >> 2, c2 = (l & 3) * 8;

  floatx4 acc[4][4];
  #pragma unroll
  for (int i = 0; i < 4; ++i)
    #pragma unroll
    for (int j = 0; j < 4; ++j) acc[i][j] = (floatx4){0.f, 0.f, 0.f, 0.f};

  for (int kk = 0; kk < KDIM; kk += 32) {
    __syncthreads();
    #pragma unroll
    for (int half = 0; half < 2; ++half) {
      int rloc = w * 32 + half * 16;
      async_copy16(&sm.ab.Al[rloc * 32], Ag + (size_t)(rloc + rsub) * KDIM + kk + c2);
      async_copy16(&sm.ab.Bl[rloc * 32], Bg + (size_t)(rloc + rsub) * KDIM + kk + c2);
    }
    __syncthreads();
    bf16x8 af[4], bfr[4];
    #pragma unroll
    for (int mt = 0; mt < 4; ++mt)
      af[mt] = *(const bf16x8*)&sm.ab.Al[(wr * 64 + mt * 16 + lane15) * 32 + quad * 8];
    #pragma unroll
    for (int nt = 0; nt < 4; ++nt)
      bfr[nt] = *(const bf16x8*)&sm.ab.Bl[(wc * 64 + nt * 16 + lane15) * 32 + quad * 8];
    #pragma unroll
    for (int mt = 0; mt < 4; ++mt)
      #pragma unroll
      for (int nt = 0; nt < 4; ++nt)
        acc[mt][nt] = mfma16(af[mt], bfr[nt], acc[mt][nt]);
  }
  __syncthreads();   // Al/Bl reads done before Cl (aliased) is written

  int proj = (cb * 128) >> 10;                 // uniform per block
  const float* bias = proj == 0 ? bq : (proj == 1 ? bk : bvv);
  float scale = proj == 0 ? 0.125f * 1.44269504088896f : 1.0f;
  bool isV = (proj == 2);

  #pragma unroll
  for (int nt = 0; nt < 4; ++nt) {
    int c = wc * 64 + nt * 16 + lane15;
    int cip = (cb * 128 + c) & 1023;
    float bias_v = bias[cip];
    #pragma unroll
    for (int mt = 0; mt < 4; ++mt) {
      #pragma unroll
      for (int r = 0; r < 4; ++r) {
        int n = wr * 64 + mt * 16 + quad * 4 + r;
        float val = (acc[mt][nt][r] + bias_v) * scale;
        if (!isV) sm.Cl[n * 136 + c] = f2b(val);
        else      sm.Cl[c * 136 + (n & 1) * 64 + (n >> 1)] = f2b(val);
      }
    }
  }
  __syncthreads();

  if (!isV) {
    ushort* dst = proj == 0 ? Qs : Ks;
    int b = t >> 7;
    int sl = t & 63;
    int chunk = (t >> 6) & 1;
    int n = (sl << 1) | b;
    int cip = (cb * 128 + chunk * 64) & 1023;
    int h = cip >> 6;
    int s = rb * 64 + sl;
    ushort* g = dst + (((size_t)(b * NH + h) * SEQ + s) * DKD);
    const uint4* s4 = (const uint4*)&sm.Cl[n * 136 + chunk * 64];
    #pragma unroll
    for (int j = 0; j < 8; ++j) *(uint4*)(g + j * 8) = s4[j];
  } else {
    int c = t >> 1, b = t & 1;
    int cip = (cb * 128 + c) & 1023;
    int h = cip >> 6, dk = c & 63;
    ushort* g = Vt + ((size_t)(b * NH + h) * DKD + dk) * SEQ + rb * 64;
    const uint4* s4 = (const uint4*)&sm.Cl[c * 136 + b * 64];
    #pragma unroll
    for (int j = 0; j < 8; ++j) *(uint4*)(g + j * 8) = s4[j];
  }
}

// ---------------- fused causal attention with softmax-one -------------------
// Round-9 per-iteration body (swizzled global_load_lds double buffer, S^T-in-
// registers P, fixed-bias exp2 softmax, deferred max) but UNPAIRED q-tiles:
// grid (bh=32 fast, 32 q-tiles) = 1024 blocks -> 4 blocks/CU = 16 waves/CU
// (2x round 9). Block for q-tile qt runs qt+1 iterations; qt = 31-blockIdx.y
// dispatches longest blocks first (LPT balancing via dynamic scheduling).
__global__ __launch_bounds__(256, 4) void attn_kernel(
    const ushort* __restrict__ Qs, const ushort* __restrict__ Ks,
    const ushort* __restrict__ Vt, float* __restrict__ out) {
  __shared__ ushort Kl[2][64 * 64];
  __shared__ ushort Vl[2][64 * 64];
  const int t = threadIdx.x;
  const int w = t >> 6, l = t & 63;
  const int lane15 = l & 15, quad = l >> 4;
  const int bh = blockIdx.x;            // fast dim -> K/V locality per XCD
  const int qt = 31 - blockIdx.y;       // longest-first dispatch
  const int b = bh >> 4, h = bh & 15;

  const ushort* Kg = Ks + (size_t)bh * SEQ * DKD;
  const ushort* Vg = Vt + (size_t)bh * DKD * SEQ;
  const int g8 = l >> 3;                // row within 8-row staging group
  const int gch = ((l & 7) ^ g8) * 8;   // swizzled global chunk (shorts)
  const int sw = lane15 & 7;            // fragment-read swizzle

  const int qbase = qt * 64;
  const ushort* Qg = Qs + ((size_t)bh * SEQ + qbase + w * 16 + lane15) * DKD;
  bf16x8 qf0 = *(const bf16x8*)(Qg + quad * 8);
  bf16x8 qf1 = *(const bf16x8*)(Qg + 32 + quad * 8);

  floatx4 o[4];
  #pragma unroll
  for (int i = 0; i < 4; ++i) o[i] = (floatx4){0.f, 0.f, 0.f, 0.f};
  floatx4 lacc = (floatx4){0.f, 0.f, 0.f, 0.f};
  float pm = -1e30f;                    // per-lane deferred max (q = lane15)

  bf16x4 ones4;
  #pragma unroll
  for (int j = 0; j < 4; ++j) ones4[j] = (short)0x3F80;  // bf16 1.0

  // async stage 64x64 K and V tiles: 4 waves x 2 calls x 8 rows each.
  #define STAGE(BUF, KT) do {                                                \
    _Pragma("unroll")                                                        \
    for (int c = 0; c < 2; ++c) {                                            \
      int rr = w * 16 + c * 8;                                               \
      async_copy16(&Kl[BUF][rr * 64],                                        \
                   Kg + (size_t)((KT) * 64 + rr + g8) * DKD + gch);          \
      async_copy16(&Vl[BUF][rr * 64],                                        \
                   Vg + (size_t)(rr + g8) * SEQ + (KT) * 64 + gch);          \
    } } while (0)

  STAGE(0, 0);

  for (int it = 0; it <= qt; ++it) {
    const int cur = it & 1;
    __syncthreads();                    // drains last iter's loads (vmcnt)
    if (it < qt) STAGE(cur ^ 1, it + 1);

    // S^T tile: A = K-frag (m = k_s), B = Q-frag (n = q)
    floatx4 sf[4];
    #pragma unroll
    for (int nt = 0; nt < 4; ++nt) {
      floatx4 a = (floatx4){-BIAS, -BIAS, -BIAS, -BIAS};
      int row = nt * 16 + lane15;
      bf16x8 k0 = *(const bf16x8*)&Kl[cur][row * 64 + ((quad ^ sw) * 8)];
      bf16x8 k1 = *(const bf16x8*)&Kl[cur][row * 64 + (((quad + 4) ^ sw) * 8)];
      a = mfma16(k0, qf0, a);
      a = mfma16(k1, qf1, a);
      sf[nt] = a;   // (k = it*64+nt*16+quad*4+r, q = qbase+w*16+lane15)
    }

    if (it == qt) {  // diagonal tile: causal mask (k > q)
      int q_abs = qbase + w * 16 + lane15;
      #pragma unroll
      for (int nt = 0; nt < 4; ++nt)
        #pragma unroll
        for (int r = 0; r < 4; ++r) {
          int k_abs = it * 64 + nt * 16 + quad * 4 + r;
          if (k_abs > q_abs) sf[nt][r] = -1e30f;
        }
    }

    // exp2 + deferred per-lane max + pack to bf16x4 A-fragments
    bf16x4 pa[4];
    #pragma unroll
    for (int nt = 0; nt < 4; ++nt) {
      float p0 = __builtin_amdgcn_exp2f(sf[nt][0]);
      float p1 = __builtin_amdgcn_exp2f(sf[nt][1]);
      float p2 = __builtin_amdgcn_exp2f(sf[nt][2]);
      float p3 = __builtin_amdgcn_exp2f(sf[nt][3]);
      pm = fmaxf(pm, fmaxf(fmaxf(sf[nt][0], sf[nt][1]),
                           fmaxf(sf[nt][2], sf[nt][3])));
      unsigned u0 = __builtin_bit_cast(unsigned, p0);
      unsigned u1 = __builtin_bit_cast(unsigned, p1);
      unsigned u2 = __builtin_bit_cast(unsigned, p2);
      unsigned u3 = __builtin_bit_cast(unsigned, p3);
      uint2v pk;
      pk[0] = (u0 >> 16) | (u1 & 0xffff0000u);
      pk[1] = (u2 >> 16) | (u3 & 0xffff0000u);
      pa[nt] = __builtin_bit_cast(bf16x4, pk);
    }

    // row-sum via MFMA (ones B) and PV, P consumed directly from registers
    #pragma unroll
    for (int nt = 0; nt < 4; ++nt) lacc = mfma16k(pa[nt], ones4, lacc);
    #pragma unroll
    for (int ntd = 0; ntd < 4; ++ntd) {
      int row = ntd * 16 + lane15;
      #pragma unroll
      for (int nt = 0; nt < 4; ++nt) {
        int ch = nt * 2 + (quad >> 1);
        bf16x4 vf = *(const bf16x4*)&Vl[cur][row * 64 + ((ch ^ sw) * 8) +
                                            (quad & 1) * 4];
        o[ntd] = mfma16k(pa[nt], vf, o[ntd]);
      }
    }
  }

  // flush q-tile
  {
    float pmr = fmaxf(pm, __shfl_xor(pm, 16, 64));
    pmr = fmaxf(pmr, __shfl_xor(pmr, 32, 64));
    float inv_[4];
    #pragma unroll
    for (int r = 0; r < 4; ++r) {
      float mq = __shfl(pmr, quad * 4 + r, 64);  // max for q = quad*4+r
      inv_[r] = 1.0f / (__builtin_amdgcn_exp2f(mq) + lacc[r]);
    }
    #pragma unroll
    for (int ntd = 0; ntd < 4; ++ntd) {
      int d = h * DKD + ntd * 16 + lane15;
      #pragma unroll
      for (int r = 0; r < 4; ++r) {
        int i = qbase + w * 16 + quad * 4 + r;
        out[((size_t)i * BSZ + b) * DM + d] = o[ntd][r] * inv_[r];
      }
    }
  }
  #undef STAGE
}

extern "C" void kernel_launch(void* const* d_in, const int* in_sizes, int n_in,
                              void* d_out, int out_size, void* d_ws, size_t ws_size,
                              hipStream_t stream) {
  (void)in_sizes; (void)n_in; (void)out_size; (void)ws_size;
  const float* x  = (const float*)d_in[0];
  const float* Wq = (const float*)d_in[1];
  const float* bq = (const float*)d_in[2];
  const float* Wk = (const float*)d_in[3];
  const float* bk = (const float*)d_in[4];
  const float* Wv = (const float*)d_in[5];
  const float* bv = (const float*)d_in[6];
  float* out = (float*)d_out;

  // cvt staging lives inside d_out (16 MB): xbf 8 MB + wbf 6 MB.
  ushort* xbf = (ushort*)d_out;                       // [0, 8 MB)
  ushort* wbf = (ushort*)((char*)d_out + 8388608);    // [8 MB, 14.67 MB)

  // d_ws usage: 24 MB total.
  char* ws = (char*)d_ws;
  ushort* Qs = (ushort*)(ws);               // [0, 8 MB)
  ushort* Ks = (ushort*)(ws + 8388608);     // [8 MB, 16 MB)
  ushort* Vt = (ushort*)(ws + 16777216);    // [16 MB, 24 MB)

  cvt_kernel<<<dim3(7168), dim3(256), 0, stream>>>(x, Wq, Wk, Wv, xbf, wbf);
  gemm_qkv<<<dim3(32, 24), dim3(256), 0, stream>>>(xbf, wbf, bq, bk, bv, Qs, Ks, Vt);
  attn_kernel<<<dim3(32, 32), dim3(256), 0, stream>>>(Qs, Ks, Vt, out);
}